// Round 1
// baseline (9422.193 us; speedup 1.0000x reference)
//
#include <hip/hip_runtime.h>
#include <hip/hip_bf16.h>
#include <cstddef>

#define F_ACC  1
#define F_RELU 2

#define TM 64
#define TN 64
#define TK 16
#define LDSP 68   // padded LDS row: 68*4B per row keeps float4 alignment, breaks 4-way write conflicts

// C[M,N] = op( rowscale(A) @ W + bias [+ C] ), op = optional relu
// A: [M,K] row-major, W: [K,N] row-major. N multiple of 64, K multiple of 16.
__global__ __launch_bounds__(256) void gemm_kernel(
    const float* __restrict__ A, const float* __restrict__ W,
    const float* __restrict__ bias, const float* __restrict__ rowscale,
    float* __restrict__ C, int M, int N, int K, int flags)
{
    __shared__ float As[TK][LDSP];
    __shared__ float Bs[TK][LDSP];
    const int tid = threadIdx.x;
    const int bm = blockIdx.x * TM;
    const int bn = blockIdx.y * TN;
    const int ty = tid >> 4;          // 0..15 (row group of 4)
    const int tx = tid & 15;          // 0..15 (col group of 4)
    const int a_row = tid >> 2;       // 0..63
    const int a_k   = (tid & 3) << 2; // 0,4,8,12
    const int b_k   = tid >> 4;       // 0..15
    const int b_c   = (tid & 15) << 2;

    float acc[4][4] = {{0.f,0.f,0.f,0.f},{0.f,0.f,0.f,0.f},{0.f,0.f,0.f,0.f},{0.f,0.f,0.f,0.f}};

    const int arow_g = bm + a_row;
    const bool a_ok = (arow_g < M);
    float rs = 1.0f;
    if (rowscale != nullptr && a_ok) rs = rowscale[arow_g];
    const float* Ap = A + (size_t)(a_ok ? arow_g : 0) * K + a_k;
    const float* Wp = W + (size_t)b_k * N + bn + b_c;

    for (int k0 = 0; k0 < K; k0 += TK) {
        float4 av = make_float4(0.f, 0.f, 0.f, 0.f);
        if (a_ok) av = *(const float4*)(Ap + k0);
        As[a_k + 0][a_row] = av.x * rs;
        As[a_k + 1][a_row] = av.y * rs;
        As[a_k + 2][a_row] = av.z * rs;
        As[a_k + 3][a_row] = av.w * rs;
        float4 bv = *(const float4*)(Wp + (size_t)k0 * N);
        *(float4*)&Bs[b_k][b_c] = bv;
        __syncthreads();
#pragma unroll
        for (int k = 0; k < TK; ++k) {
            float4 a4 = *(const float4*)&As[k][ty << 2];
            float4 b4 = *(const float4*)&Bs[k][tx << 2];
            acc[0][0] += a4.x * b4.x; acc[0][1] += a4.x * b4.y; acc[0][2] += a4.x * b4.z; acc[0][3] += a4.x * b4.w;
            acc[1][0] += a4.y * b4.x; acc[1][1] += a4.y * b4.y; acc[1][2] += a4.y * b4.z; acc[1][3] += a4.y * b4.w;
            acc[2][0] += a4.z * b4.x; acc[2][1] += a4.z * b4.y; acc[2][2] += a4.z * b4.z; acc[2][3] += a4.z * b4.w;
            acc[3][0] += a4.w * b4.x; acc[3][1] += a4.w * b4.y; acc[3][2] += a4.w * b4.z; acc[3][3] += a4.w * b4.w;
        }
        __syncthreads();
    }

#pragma unroll
    for (int i = 0; i < 4; ++i) {
        int row = bm + (ty << 2) + i;
        if (row >= M) continue;
        int col = bn + (tx << 2);
        float4 c4 = make_float4(acc[i][0], acc[i][1], acc[i][2], acc[i][3]);
        if (bias != nullptr) {
            float4 bb = *(const float4*)(bias + col);
            c4.x += bb.x; c4.y += bb.y; c4.z += bb.z; c4.w += bb.w;
        }
        float* Cp = C + (size_t)row * N + col;
        if (flags & F_ACC) {
            float4 o = *(const float4*)Cp;
            c4.x += o.x; c4.y += o.y; c4.z += o.z; c4.w += o.w;
        }
        if (flags & F_RELU) {
            c4.x = fmaxf(c4.x, 0.f); c4.y = fmaxf(c4.y, 0.f);
            c4.z = fmaxf(c4.z, 0.f); c4.w = fmaxf(c4.w, 0.f);
        }
        *(float4*)Cp = c4;
    }
}

// one thread per edge: degree count
__global__ void count_edges(const int* __restrict__ dst, int E, int* __restrict__ cnt)
{
    int i = blockIdx.x * blockDim.x + threadIdx.x;
    if (i < E) atomicAdd(&cnt[dst[i]], 1);
}

__global__ void make_inv(const int* __restrict__ cnt, float* __restrict__ inv, int n)
{
    int i = blockIdx.x * blockDim.x + threadIdx.x;
    if (i < n) {
        int c = cnt[i];
        inv[i] = 1.0f / (float)(c > 1 ? c : 1);
    }
}

// wave (64 lanes) per edge, lane covers 4 floats: gather row src, atomic-scatter to row dst
__global__ __launch_bounds__(256) void scatter_add(
    const float* __restrict__ X, const int* __restrict__ src, const int* __restrict__ dst,
    int E, float* __restrict__ Mo)
{
    long long gid = (long long)blockIdx.x * blockDim.x + threadIdx.x;
    int e = (int)(gid >> 6);
    if (e >= E) return;
    int c = (threadIdx.x & 63) << 2;
    int s = src[e], d = dst[e];
    float4 v = *(const float4*)(X + (size_t)s * 256 + c);
    float* o = Mo + (size_t)d * 256 + c;
    atomicAdd(o + 0, v.x); atomicAdd(o + 1, v.y);
    atomicAdd(o + 2, v.z); atomicAdd(o + 3, v.w);
}

__global__ void wsum_kernel(const float* __restrict__ Wa, const float* __restrict__ Wb,
                            float* __restrict__ Wo, const float* __restrict__ ba,
                            const float* __restrict__ bb, float* __restrict__ bo,
                            int nW, int nb)
{
    int i = blockIdx.x * blockDim.x + threadIdx.x;
    if (i < nW) Wo[i] = Wa[i] + Wb[i];
    if (i < nb) bo[i] = ba[i] + bb[i];
}

// wave per row: scores[i] = dot(s_att[i,:], c_att[batch[i],:]); atomicMax encoded max per batch
__global__ __launch_bounds__(256) void scores_kernel(
    const float* __restrict__ s_att, const float* __restrict__ c_att,
    const int* __restrict__ batch, float* __restrict__ scores,
    unsigned int* __restrict__ smax, int Ns)
{
    long long gid = (long long)blockIdx.x * blockDim.x + threadIdx.x;
    int row = (int)(gid >> 6);
    if (row >= Ns) return;
    int lane = threadIdx.x & 63;
    int b = batch[row];
    float4 s4 = *(const float4*)(s_att + (size_t)row * 256 + (lane << 2));
    float4 c4 = *(const float4*)(c_att + (size_t)b * 256 + (lane << 2));
    float p = s4.x * c4.x + s4.y * c4.y + s4.z * c4.z + s4.w * c4.w;
#pragma unroll
    for (int off = 32; off > 0; off >>= 1) p += __shfl_down(p, off, 64);
    if (lane == 0) {
        scores[row] = p;
        unsigned bits = __float_as_uint(p);
        unsigned key = (bits & 0x80000000u) ? ~bits : (bits | 0x80000000u);
        atomicMax(&smax[b], key);
    }
}

__global__ void exp_kernel(float* __restrict__ scores, const unsigned int* __restrict__ smax,
                           const int* __restrict__ batch, float* __restrict__ denom, int Ns)
{
    int i = blockIdx.x * blockDim.x + threadIdx.x;
    if (i >= Ns) return;
    int b = batch[i];
    unsigned u = smax[b];
    unsigned bits = (u & 0x80000000u) ? (u & 0x7fffffffu) : ~u;
    float mx = __uint_as_float(bits);
    float e = expf(scores[i] - mx);
    scores[i] = e;
    atomicAdd(&denom[b], e);
}

// wave per row: g[batch[i]] += (e[i]/denom[b]) * xs[i]
__global__ __launch_bounds__(256) void g_kernel(
    const float* __restrict__ e, const float* __restrict__ denom,
    const int* __restrict__ batch, const float* __restrict__ xs,
    float* __restrict__ g, int Ns)
{
    long long gid = (long long)blockIdx.x * blockDim.x + threadIdx.x;
    int row = (int)(gid >> 6);
    if (row >= Ns) return;
    int lane = threadIdx.x & 63;
    int b = batch[row];
    float alpha = e[row] / denom[b];
    float4 x4 = *(const float4*)(xs + (size_t)row * 256 + (lane << 2));
    float* gp = g + (size_t)b * 256 + (lane << 2);
    atomicAdd(gp + 0, alpha * x4.x); atomicAdd(gp + 1, alpha * x4.y);
    atomicAdd(gp + 2, alpha * x4.z); atomicAdd(gp + 3, alpha * x4.w);
}

__global__ void z_kernel(const float* __restrict__ ch, const float* __restrict__ g,
                         float* __restrict__ z, int B, int H)
{
    int i = blockIdx.x * blockDim.x + threadIdx.x;
    if (i >= B * H) return;
    int b = i / H, c = i % H;
    float cv = ch[i], gv = g[i];
    float* zr = z + (size_t)b * 4 * H;
    zr[c]         = cv;
    zr[H + c]     = gv;
    zr[2 * H + c] = fabsf(cv - gv);
    zr[3 * H + c] = cv * gv;
}

__global__ void out_kernel(const float* __restrict__ h, const float* __restrict__ W2,
                           const float* __restrict__ b2, float* __restrict__ out, int B, int H)
{
    int i = blockIdx.x * blockDim.x + threadIdx.x;
    if (i >= B * 2) return;
    int b = i >> 1, j = i & 1;
    float s = b2[j];
    const float* hr = h + (size_t)b * H;
    for (int k = 0; k < H; ++k) s += hr[k] * W2[k * 2 + j];
    out[i] = s;
}

extern "C" void kernel_launch(void* const* d_in, const int* in_sizes, int n_in,
                              void* d_out, int out_size, void* d_ws, size_t ws_size,
                              hipStream_t stream)
{
    const float* x_s    = (const float*)d_in[0];
    const float* x_n    = (const float*)d_in[1];
    const float* claim  = (const float*)d_in[2];
    const int*   batch_s= (const int*)d_in[3];
    const int*   src_ss = (const int*)d_in[4];
    const int*   dst_ss = (const int*)d_in[5];
    const int*   src_sn = (const int*)d_in[6];
    const int*   dst_sn = (const int*)d_in[7];
    const int*   src_ns = (const int*)d_in[8];
    const int*   dst_ns = (const int*)d_in[9];
    const float* W_ps   = (const float*)d_in[10];
    const float* b_ps   = (const float*)d_in[11];
    const float* W_pn   = (const float*)d_in[12];
    const float* b_pn   = (const float*)d_in[13];
    const float* W_pc   = (const float*)d_in[14];
    const float* b_pc   = (const float*)d_in[15];
    const float* conv_Wl= (const float*)d_in[16];
    const float* conv_bl= (const float*)d_in[17];
    const float* conv_Wr= (const float*)d_in[18];
    const float* W_attc = (const float*)d_in[19];
    const float* W_atts = (const float*)d_in[20];
    const float* W1     = (const float*)d_in[21];
    const float* b1     = (const float*)d_in[22];
    const float* W2     = (const float*)d_in[23];
    const float* b2     = (const float*)d_in[24];

    const int in_dim = 768, H = 256;
    const int Ns  = in_sizes[0] / in_dim;
    const int Ne  = in_sizes[1] / in_dim;
    const int B   = in_sizes[2] / in_dim;
    const int Ess = in_sizes[4];
    const int Esn = in_sizes[6];
    const int Ens = in_sizes[8];
    const int L   = in_sizes[16] / (3 * H * H);
    const int Nmax = (Ns > Ne) ? Ns : Ne;

    float* ws = (float*)d_ws;
    size_t off = 0;
    auto alloc = [&](size_t n) { float* p = ws + off; off += (n + 15) & ~(size_t)15; return p; };
    float* xs_a  = alloc((size_t)Ns * H);
    float* xs_b  = alloc((size_t)Ns * H);
    float* xn_a  = alloc((size_t)Ne * H);
    float* xn_b  = alloc((size_t)Ne * H);
    float* m_big = alloc((size_t)Nmax * H);   // reused: m_ss -> m_ns -> m_sn per layer; s_att at the end
    float* ch    = alloc((size_t)B * H);
    float* c_att = alloc((size_t)B * H);
    float* wsum  = alloc((size_t)H * H);
    float* bsum  = alloc(H);
    int*   cnt_ss = (int*)alloc(Ns);
    int*   cnt_sn = (int*)alloc(Ne);
    int*   cnt_ns = (int*)alloc(Ns);
    float* inv_ss = alloc(Ns);
    float* inv_sn = alloc(Ne);
    float* inv_ns = alloc(Ns);
    float* scores = alloc(Ns);
    unsigned int* smax = (unsigned int*)alloc(B);
    float* denom = alloc(B);
    float* g     = alloc((size_t)B * H);
    float* z     = alloc((size_t)B * 4 * H);
    float* hbuf  = alloc((size_t)B * H);
    (void)ws_size; (void)n_in; (void)out_size;

    auto gemm = [&](const float* A, const float* W, const float* bias, const float* rowscale,
                    float* C, int M, int N, int K, int flags) {
        dim3 grid((M + TM - 1) / TM, N / TN);
        gemm_kernel<<<grid, dim3(256), 0, stream>>>(A, W, bias, rowscale, C, M, N, K, flags);
    };

    // ---- degree counts (edge-list-only; reused across layers) ----
    hipMemsetAsync(cnt_ss, 0, (size_t)Ns * 4, stream);
    hipMemsetAsync(cnt_sn, 0, (size_t)Ne * 4, stream);
    hipMemsetAsync(cnt_ns, 0, (size_t)Ns * 4, stream);
    count_edges<<<(Ess + 255) / 256, 256, 0, stream>>>(dst_ss, Ess, cnt_ss);
    count_edges<<<(Esn + 255) / 256, 256, 0, stream>>>(dst_sn, Esn, cnt_sn);
    count_edges<<<(Ens + 255) / 256, 256, 0, stream>>>(dst_ns, Ens, cnt_ns);
    make_inv<<<(Ns + 255) / 256, 256, 0, stream>>>(cnt_ss, inv_ss, Ns);
    make_inv<<<(Ne + 255) / 256, 256, 0, stream>>>(cnt_sn, inv_sn, Ne);
    make_inv<<<(Ns + 255) / 256, 256, 0, stream>>>(cnt_ns, inv_ns, Ns);

    // ---- input projections ----
    gemm(x_s,   W_ps, b_ps, nullptr, xs_a, Ns, H, in_dim, F_RELU);
    gemm(x_n,   W_pn, b_pn, nullptr, xn_a, Ne, H, in_dim, F_RELU);
    gemm(claim, W_pc, b_pc, nullptr, ch,   B,  H, in_dim, F_RELU);

    // ---- GNN layers ----
    float* xs_cur = xs_a; float* xs_nxt = xs_b;
    float* xn_cur = xn_a; float* xn_nxt = xn_b;
    for (int l = 0; l < L; ++l) {
        const float* Wl = conv_Wl + (size_t)l * 3 * H * H;
        const float* bl = conv_bl + (size_t)l * 3 * H;
        const float* Wr = conv_Wr + (size_t)l * 3 * H * H;

        // Wsum = Wr[ss] + Wr[ns], bsum = bl[ss] + bl[ns]  (HeteroConv sum on sentence)
        wsum_kernel<<<(H * H + 255) / 256, 256, 0, stream>>>(
            Wr, Wr + 2 * (size_t)H * H, wsum, bl, bl + 2 * H, bsum, H * H, H);

        // m_ss = scatter(xs via ss)  -> xs_nxt = inv_ss*m_ss @ Wl[ss] + bsum
        hipMemsetAsync(m_big, 0, (size_t)Ns * H * 4, stream);
        scatter_add<<<(unsigned)(((long long)Ess * 64 + 255) / 256), 256, 0, stream>>>(
            xs_cur, src_ss, dst_ss, Ess, m_big);
        gemm(m_big, Wl, bsum, inv_ss, xs_nxt, Ns, H, H, 0);

        // m_ns = scatter(xn via ns)  -> xs_nxt += inv_ns*m_ns @ Wl[ns]
        hipMemsetAsync(m_big, 0, (size_t)Ns * H * 4, stream);
        scatter_add<<<(unsigned)(((long long)Ens * 64 + 255) / 256), 256, 0, stream>>>(
            xn_cur, src_ns, dst_ns, Ens, m_big);
        gemm(m_big, Wl + 2 * (size_t)H * H, nullptr, inv_ns, xs_nxt, Ns, H, H, F_ACC);

        // xs_nxt += xs_cur @ (Wr[ss]+Wr[ns]); relu
        gemm(xs_cur, wsum, nullptr, nullptr, xs_nxt, Ns, H, H, F_ACC | F_RELU);

        // m_sn = scatter(xs via sn) -> xn_nxt = inv_sn*m_sn @ Wl[sn] + bl[sn]; += xn_cur @ Wr[sn]; relu
        hipMemsetAsync(m_big, 0, (size_t)Ne * H * 4, stream);
        scatter_add<<<(unsigned)(((long long)Esn * 64 + 255) / 256), 256, 0, stream>>>(
            xs_cur, src_sn, dst_sn, Esn, m_big);
        gemm(m_big, Wl + (size_t)H * H, bl + H, inv_sn, xn_nxt, Ne, H, H, 0);
        gemm(xn_cur, Wr + (size_t)H * H, nullptr, nullptr, xn_nxt, Ne, H, H, F_ACC | F_RELU);

        float* t;
        t = xs_cur; xs_cur = xs_nxt; xs_nxt = t;
        t = xn_cur; xn_cur = xn_nxt; xn_nxt = t;
    }

    // ---- attentive pooling ----
    gemm(ch,     W_attc, nullptr, nullptr, c_att, B,  H, H, 0);
    gemm(xs_cur, W_atts, nullptr, nullptr, m_big, Ns, H, H, 0);   // s_att in m_big
    hipMemsetAsync(smax,  0, (size_t)B * 4, stream);
    hipMemsetAsync(denom, 0, (size_t)B * 4, stream);
    hipMemsetAsync(g,     0, (size_t)B * H * 4, stream);
    scores_kernel<<<(unsigned)(((long long)Ns * 64 + 255) / 256), 256, 0, stream>>>(
        m_big, c_att, batch_s, scores, smax, Ns);
    exp_kernel<<<(Ns + 255) / 256, 256, 0, stream>>>(scores, smax, batch_s, denom, Ns);
    g_kernel<<<(unsigned)(((long long)Ns * 64 + 255) / 256), 256, 0, stream>>>(
        scores, denom, batch_s, xs_cur, g, Ns);

    // ---- head MLP ----
    z_kernel<<<(B * H + 255) / 256, 256, 0, stream>>>(ch, g, z, B, H);
    gemm(z, W1, b1, nullptr, hbuf, B, H, 4 * H, F_RELU);
    out_kernel<<<(B * 2 + 255) / 256, 256, 0, stream>>>(hbuf, W2, b2, (float*)d_out, B, H);
}

// Round 2
// 3005.916 us; speedup vs baseline: 3.1346x; 3.1346x over previous
//
#include <hip/hip_runtime.h>
#include <hip/hip_bf16.h>
#include <cstddef>

#define F_ACC  1
#define F_RELU 2

#define TM 64
#define TN 64
#define TK 16
#define LDSP 68   // padded LDS row: breaks 4-way write conflicts, keeps float4 alignment

// C[M,N] = op( A @ W + bias [+ C] ), op = optional relu
// A: [M,K] row-major, W: [K,N] row-major. N multiple of 64, K multiple of 16.
__global__ __launch_bounds__(256) void gemm_kernel(
    const float* __restrict__ A, const float* __restrict__ W,
    const float* __restrict__ bias,
    float* __restrict__ C, int M, int N, int K, int flags)
{
    __shared__ float As[TK][LDSP];
    __shared__ float Bs[TK][LDSP];
    const int tid = threadIdx.x;
    const int bm = blockIdx.x * TM;
    const int bn = blockIdx.y * TN;
    const int ty = tid >> 4;          // 0..15
    const int tx = tid & 15;          // 0..15
    const int a_row = tid >> 2;       // 0..63
    const int a_k   = (tid & 3) << 2; // 0,4,8,12
    const int b_k   = tid >> 4;       // 0..15
    const int b_c   = (tid & 15) << 2;

    float acc[4][4] = {{0.f,0.f,0.f,0.f},{0.f,0.f,0.f,0.f},{0.f,0.f,0.f,0.f},{0.f,0.f,0.f,0.f}};

    const int arow_g = bm + a_row;
    const bool a_ok = (arow_g < M);
    const float* Ap = A + (size_t)(a_ok ? arow_g : 0) * K + a_k;
    const float* Wp = W + (size_t)b_k * N + bn + b_c;

    for (int k0 = 0; k0 < K; k0 += TK) {
        float4 av = make_float4(0.f, 0.f, 0.f, 0.f);
        if (a_ok) av = *(const float4*)(Ap + k0);
        As[a_k + 0][a_row] = av.x;
        As[a_k + 1][a_row] = av.y;
        As[a_k + 2][a_row] = av.z;
        As[a_k + 3][a_row] = av.w;
        float4 bv = *(const float4*)(Wp + (size_t)k0 * N);
        *(float4*)&Bs[b_k][b_c] = bv;
        __syncthreads();
#pragma unroll
        for (int k = 0; k < TK; ++k) {
            float4 a4 = *(const float4*)&As[k][ty << 2];
            float4 b4 = *(const float4*)&Bs[k][tx << 2];
            acc[0][0] += a4.x * b4.x; acc[0][1] += a4.x * b4.y; acc[0][2] += a4.x * b4.z; acc[0][3] += a4.x * b4.w;
            acc[1][0] += a4.y * b4.x; acc[1][1] += a4.y * b4.y; acc[1][2] += a4.y * b4.z; acc[1][3] += a4.y * b4.w;
            acc[2][0] += a4.z * b4.x; acc[2][1] += a4.z * b4.y; acc[2][2] += a4.z * b4.z; acc[2][3] += a4.z * b4.w;
            acc[3][0] += a4.w * b4.x; acc[3][1] += a4.w * b4.y; acc[3][2] += a4.w * b4.z; acc[3][3] += a4.w * b4.w;
        }
        __syncthreads();
    }

#pragma unroll
    for (int i = 0; i < 4; ++i) {
        int row = bm + (ty << 2) + i;
        if (row >= M) continue;
        int col = bn + (tx << 2);
        float4 c4 = make_float4(acc[i][0], acc[i][1], acc[i][2], acc[i][3]);
        if (bias != nullptr) {
            float4 bb = *(const float4*)(bias + col);
            c4.x += bb.x; c4.y += bb.y; c4.z += bb.z; c4.w += bb.w;
        }
        float* Cp = C + (size_t)row * N + col;
        if (flags & F_ACC) {
            float4 o = *(const float4*)Cp;
            c4.x += o.x; c4.y += o.y; c4.z += o.z; c4.w += o.w;
        }
        if (flags & F_RELU) {
            c4.x = fmaxf(c4.x, 0.f); c4.y = fmaxf(c4.y, 0.f);
            c4.z = fmaxf(c4.z, 0.f); c4.w = fmaxf(c4.w, 0.f);
        }
        *(float4*)Cp = c4;
    }
}

// ---------------- CSR construction ----------------

__global__ void count_edges(const int* __restrict__ dst, int E, int* __restrict__ cnt)
{
    int i = blockIdx.x * blockDim.x + threadIdx.x;
    if (i < E) atomicAdd(&cnt[dst[i]], 1);
}

__global__ void make_inv(const int* __restrict__ cnt, float* __restrict__ inv, int n)
{
    int i = blockIdx.x * blockDim.x + threadIdx.x;
    if (i < n) {
        int c = cnt[i];
        inv[i] = 1.0f / (float)(c > 1 ? c : 1);
    }
}

// block-wise inclusive scan (Hillis-Steele in LDS); out[i+1] = partial inclusive
__global__ void scan1(const int* __restrict__ cnt, int n, int* __restrict__ rowptr,
                      int* __restrict__ bsums)
{
    __shared__ int tmp[256];
    int i = blockIdx.x * 256 + threadIdx.x;
    tmp[threadIdx.x] = (i < n) ? cnt[i] : 0;
    __syncthreads();
    for (int off = 1; off < 256; off <<= 1) {
        int t = (threadIdx.x >= (unsigned)off) ? tmp[threadIdx.x - off] : 0;
        __syncthreads();
        tmp[threadIdx.x] += t;
        __syncthreads();
    }
    if (i < n) rowptr[i + 1] = tmp[threadIdx.x];
    if (threadIdx.x == 255) bsums[blockIdx.x] = tmp[255];
}

// single-block inclusive scan of block sums (nb <= a few hundred)
__global__ void scan2(int* __restrict__ bsums, int nb)
{
    __shared__ int tmp[256];
    __shared__ int carry;
    if (threadIdx.x == 0) carry = 0;
    __syncthreads();
    for (int base = 0; base < nb; base += 256) {
        int i = base + threadIdx.x;
        tmp[threadIdx.x] = (i < nb) ? bsums[i] : 0;
        __syncthreads();
        for (int off = 1; off < 256; off <<= 1) {
            int t = (threadIdx.x >= (unsigned)off) ? tmp[threadIdx.x - off] : 0;
            __syncthreads();
            tmp[threadIdx.x] += t;
            __syncthreads();
        }
        int c = carry;
        if (i < nb) bsums[i] = tmp[threadIdx.x] + c;
        __syncthreads();
        if (threadIdx.x == 255) carry = c + tmp[255];
        __syncthreads();
    }
}

__global__ void scan3(int* __restrict__ rowptr, const int* __restrict__ bsums, int n)
{
    int i = blockIdx.x * 256 + threadIdx.x;
    if (i == 0) rowptr[0] = 0;
    if (i < n && blockIdx.x > 0) rowptr[i + 1] += bsums[blockIdx.x - 1];
}

__global__ void csr_fill(const int* __restrict__ src, const int* __restrict__ dst, int E,
                         const int* __restrict__ rowptr, int* __restrict__ fillc,
                         int* __restrict__ col)
{
    int e = blockIdx.x * blockDim.x + threadIdx.x;
    if (e < E) {
        int d = dst[e];
        int p = atomicAdd(&fillc[d], 1);
        col[rowptr[d] + p] = src[e];
    }
}

// ---------------- CSR mean-aggregation (gather, no atomics) ----------------
// one wave per destination row; lane covers 4 contiguous floats
__global__ __launch_bounds__(256) void gather_mean(
    const float* __restrict__ X, const int* __restrict__ rowptr,
    const int* __restrict__ col, const float* __restrict__ inv,
    float* __restrict__ out, int Nd)
{
    long long gid = (long long)blockIdx.x * blockDim.x + threadIdx.x;
    int row = (int)(gid >> 6);
    if (row >= Nd) return;
    int c = (threadIdx.x & 63) << 2;
    int e0 = rowptr[row], e1 = rowptr[row + 1];
    float4 acc = make_float4(0.f, 0.f, 0.f, 0.f);
    for (int e = e0; e < e1; ++e) {
        int s = col[e];   // wave-uniform
        float4 v = *(const float4*)(X + (size_t)s * 256 + c);
        acc.x += v.x; acc.y += v.y; acc.z += v.z; acc.w += v.w;
    }
    float sc = inv[row];
    acc.x *= sc; acc.y *= sc; acc.z *= sc; acc.w *= sc;
    *(float4*)(out + (size_t)row * 256 + c) = acc;
}

// ---------------- misc small kernels ----------------

__global__ void wsum_kernel(const float* __restrict__ Wa, const float* __restrict__ Wb,
                            float* __restrict__ Wo, const float* __restrict__ ba,
                            const float* __restrict__ bb, float* __restrict__ bo,
                            int nW, int nb)
{
    int i = blockIdx.x * blockDim.x + threadIdx.x;
    if (i < nW) Wo[i] = Wa[i] + Wb[i];
    if (i < nb) bo[i] = ba[i] + bb[i];
}

__global__ __launch_bounds__(256) void scores_kernel(
    const float* __restrict__ s_att, const float* __restrict__ c_att,
    const int* __restrict__ batch, float* __restrict__ scores,
    unsigned int* __restrict__ smax, int Ns)
{
    long long gid = (long long)blockIdx.x * blockDim.x + threadIdx.x;
    int row = (int)(gid >> 6);
    if (row >= Ns) return;
    int lane = threadIdx.x & 63;
    int b = batch[row];
    float4 s4 = *(const float4*)(s_att + (size_t)row * 256 + (lane << 2));
    float4 c4 = *(const float4*)(c_att + (size_t)b * 256 + (lane << 2));
    float p = s4.x * c4.x + s4.y * c4.y + s4.z * c4.z + s4.w * c4.w;
#pragma unroll
    for (int off = 32; off > 0; off >>= 1) p += __shfl_down(p, off, 64);
    if (lane == 0) {
        scores[row] = p;
        unsigned bits = __float_as_uint(p);
        unsigned key = (bits & 0x80000000u) ? ~bits : (bits | 0x80000000u);
        atomicMax(&smax[b], key);
    }
}

__global__ void exp_kernel(float* __restrict__ scores, const unsigned int* __restrict__ smax,
                           const int* __restrict__ batch, float* __restrict__ denom, int Ns)
{
    int i = blockIdx.x * blockDim.x + threadIdx.x;
    if (i >= Ns) return;
    int b = batch[i];
    unsigned u = smax[b];
    unsigned bits = (u & 0x80000000u) ? (u & 0x7fffffffu) : ~u;
    float mx = __uint_as_float(bits);
    float e = expf(scores[i] - mx);
    scores[i] = e;
    atomicAdd(&denom[b], e);
}

__global__ __launch_bounds__(256) void g_kernel(
    const float* __restrict__ e, const float* __restrict__ denom,
    const int* __restrict__ batch, const float* __restrict__ xs,
    float* __restrict__ g, int Ns)
{
    long long gid = (long long)blockIdx.x * blockDim.x + threadIdx.x;
    int row = (int)(gid >> 6);
    if (row >= Ns) return;
    int lane = threadIdx.x & 63;
    int b = batch[row];
    float alpha = e[row] / denom[b];
    float4 x4 = *(const float4*)(xs + (size_t)row * 256 + (lane << 2));
    float* gp = g + (size_t)b * 256 + (lane << 2);
    atomicAdd(gp + 0, alpha * x4.x); atomicAdd(gp + 1, alpha * x4.y);
    atomicAdd(gp + 2, alpha * x4.z); atomicAdd(gp + 3, alpha * x4.w);
}

__global__ void z_kernel(const float* __restrict__ ch, const float* __restrict__ g,
                         float* __restrict__ z, int B, int H)
{
    int i = blockIdx.x * blockDim.x + threadIdx.x;
    if (i >= B * H) return;
    int b = i / H, c = i % H;
    float cv = ch[i], gv = g[i];
    float* zr = z + (size_t)b * 4 * H;
    zr[c]         = cv;
    zr[H + c]     = gv;
    zr[2 * H + c] = fabsf(cv - gv);
    zr[3 * H + c] = cv * gv;
}

__global__ void out_kernel(const float* __restrict__ h, const float* __restrict__ W2,
                           const float* __restrict__ b2, float* __restrict__ out, int B, int H)
{
    int i = blockIdx.x * blockDim.x + threadIdx.x;
    if (i >= B * 2) return;
    int b = i >> 1, j = i & 1;
    float s = b2[j];
    const float* hr = h + (size_t)b * H;
    for (int k = 0; k < H; ++k) s += hr[k] * W2[k * 2 + j];
    out[i] = s;
}

extern "C" void kernel_launch(void* const* d_in, const int* in_sizes, int n_in,
                              void* d_out, int out_size, void* d_ws, size_t ws_size,
                              hipStream_t stream)
{
    const float* x_s    = (const float*)d_in[0];
    const float* x_n    = (const float*)d_in[1];
    const float* claim  = (const float*)d_in[2];
    const int*   batch_s= (const int*)d_in[3];
    const int*   src_ss = (const int*)d_in[4];
    const int*   dst_ss = (const int*)d_in[5];
    const int*   src_sn = (const int*)d_in[6];
    const int*   dst_sn = (const int*)d_in[7];
    const int*   src_ns = (const int*)d_in[8];
    const int*   dst_ns = (const int*)d_in[9];
    const float* W_ps   = (const float*)d_in[10];
    const float* b_ps   = (const float*)d_in[11];
    const float* W_pn   = (const float*)d_in[12];
    const float* b_pn   = (const float*)d_in[13];
    const float* W_pc   = (const float*)d_in[14];
    const float* b_pc   = (const float*)d_in[15];
    const float* conv_Wl= (const float*)d_in[16];
    const float* conv_bl= (const float*)d_in[17];
    const float* conv_Wr= (const float*)d_in[18];
    const float* W_attc = (const float*)d_in[19];
    const float* W_atts = (const float*)d_in[20];
    const float* W1     = (const float*)d_in[21];
    const float* b1     = (const float*)d_in[22];
    const float* W2     = (const float*)d_in[23];
    const float* b2     = (const float*)d_in[24];

    const int in_dim = 768, H = 256;
    const int Ns  = in_sizes[0] / in_dim;
    const int Ne  = in_sizes[1] / in_dim;
    const int B   = in_sizes[2] / in_dim;
    const int Ess = in_sizes[4];
    const int Esn = in_sizes[6];
    const int Ens = in_sizes[8];
    const int L   = in_sizes[16] / (3 * H * H);
    const int Nmax = (Ns > Ne) ? Ns : Ne;
    const int nb_max = (Nmax + 255) / 256;

    float* ws = (float*)d_ws;
    size_t off = 0;
    auto alloc = [&](size_t n) { float* p = ws + off; off += (n + 15) & ~(size_t)15; return p; };
    float* xs_a  = alloc((size_t)Ns * H);
    float* xs_b  = alloc((size_t)Ns * H);
    float* xn_a  = alloc((size_t)Ne * H);
    float* xn_b  = alloc((size_t)Ne * H);
    float* m_big = alloc((size_t)Nmax * H);   // gather output / s_att at the end
    float* ch    = alloc((size_t)B * H);
    float* c_att = alloc((size_t)B * H);
    float* wsum  = alloc((size_t)H * H);
    float* bsum  = alloc(H);
    int*   cnt_ss = (int*)alloc(Ns);
    int*   cnt_sn = (int*)alloc(Ne);
    int*   cnt_ns = (int*)alloc(Ns);
    float* inv_ss = alloc(Ns);
    float* inv_sn = alloc(Ne);
    float* inv_ns = alloc(Ns);
    int*   rp_ss  = (int*)alloc(Ns + 1);
    int*   rp_sn  = (int*)alloc(Ne + 1);
    int*   rp_ns  = (int*)alloc(Ns + 1);
    int*   col_ss = (int*)alloc(Ess);
    int*   col_sn = (int*)alloc(Esn);
    int*   col_ns = (int*)alloc(Ens);
    int*   fillc  = (int*)alloc(Nmax);
    int*   bsums  = (int*)alloc(nb_max);
    float* scores = alloc(Ns);
    unsigned int* smax = (unsigned int*)alloc(B);
    float* denom = alloc(B);
    float* g     = alloc((size_t)B * H);
    float* z     = alloc((size_t)B * 4 * H);
    float* hbuf  = alloc((size_t)B * H);
    (void)ws_size; (void)n_in; (void)out_size;

    auto gemm = [&](const float* A, const float* W, const float* bias,
                    float* C, int M, int N, int K, int flags) {
        dim3 grid((M + TM - 1) / TM, N / TN);
        gemm_kernel<<<grid, dim3(256), 0, stream>>>(A, W, bias, C, M, N, K, flags);
    };

    // ---- degree counts + inverse (reused across layers) ----
    hipMemsetAsync(cnt_ss, 0, (size_t)Ns * 4, stream);
    hipMemsetAsync(cnt_sn, 0, (size_t)Ne * 4, stream);
    hipMemsetAsync(cnt_ns, 0, (size_t)Ns * 4, stream);
    count_edges<<<(Ess + 255) / 256, 256, 0, stream>>>(dst_ss, Ess, cnt_ss);
    count_edges<<<(Esn + 255) / 256, 256, 0, stream>>>(dst_sn, Esn, cnt_sn);
    count_edges<<<(Ens + 255) / 256, 256, 0, stream>>>(dst_ns, Ens, cnt_ns);
    make_inv<<<(Ns + 255) / 256, 256, 0, stream>>>(cnt_ss, inv_ss, Ns);
    make_inv<<<(Ne + 255) / 256, 256, 0, stream>>>(cnt_sn, inv_sn, Ne);
    make_inv<<<(Ns + 255) / 256, 256, 0, stream>>>(cnt_ns, inv_ns, Ns);

    // ---- CSR build for each relation ----
    auto build_csr = [&](const int* src, const int* dst, int E, int Nd,
                         const int* cnt, int* rowptr, int* colidx) {
        int nb = (Nd + 255) / 256;
        scan1<<<nb, 256, 0, stream>>>(cnt, Nd, rowptr, bsums);
        scan2<<<1, 256, 0, stream>>>(bsums, nb);
        scan3<<<nb, 256, 0, stream>>>(rowptr, bsums, Nd);
        hipMemsetAsync(fillc, 0, (size_t)Nd * 4, stream);
        csr_fill<<<(E + 255) / 256, 256, 0, stream>>>(src, dst, E, rowptr, fillc, colidx);
    };
    build_csr(src_ss, dst_ss, Ess, Ns, cnt_ss, rp_ss, col_ss);
    build_csr(src_sn, dst_sn, Esn, Ne, cnt_sn, rp_sn, col_sn);
    build_csr(src_ns, dst_ns, Ens, Ns, cnt_ns, rp_ns, col_ns);

    // ---- input projections ----
    gemm(x_s,   W_ps, b_ps, xs_a, Ns, H, in_dim, F_RELU);
    gemm(x_n,   W_pn, b_pn, xn_a, Ne, H, in_dim, F_RELU);
    gemm(claim, W_pc, b_pc, ch,   B,  H, in_dim, F_RELU);

    // ---- GNN layers ----
    float* xs_cur = xs_a; float* xs_nxt = xs_b;
    float* xn_cur = xn_a; float* xn_nxt = xn_b;
    for (int l = 0; l < L; ++l) {
        const float* Wl = conv_Wl + (size_t)l * 3 * H * H;
        const float* bl = conv_bl + (size_t)l * 3 * H;
        const float* Wr = conv_Wr + (size_t)l * 3 * H * H;

        // Wsum = Wr[ss] + Wr[ns], bsum = bl[ss] + bl[ns]
        wsum_kernel<<<(H * H + 255) / 256, 256, 0, stream>>>(
            Wr, Wr + 2 * (size_t)H * H, wsum, bl, bl + 2 * H, bsum, H * H, H);

        // sentence: mean over ss -> @Wl[ss]; mean over ns -> @Wl[ns]; + xs@(Wr[ss]+Wr[ns]); relu
        gather_mean<<<(unsigned)(((long long)Ns * 64 + 255) / 256), 256, 0, stream>>>(
            xs_cur, rp_ss, col_ss, inv_ss, m_big, Ns);
        gemm(m_big, Wl, bsum, xs_nxt, Ns, H, H, 0);

        gather_mean<<<(unsigned)(((long long)Ns * 64 + 255) / 256), 256, 0, stream>>>(
            xn_cur, rp_ns, col_ns, inv_ns, m_big, Ns);
        gemm(m_big, Wl + 2 * (size_t)H * H, nullptr, xs_nxt, Ns, H, H, F_ACC);

        gemm(xs_cur, wsum, nullptr, xs_nxt, Ns, H, H, F_ACC | F_RELU);

        // entity: mean over sn -> @Wl[sn] + bl[sn]; + xn@Wr[sn]; relu
        gather_mean<<<(unsigned)(((long long)Ne * 64 + 255) / 256), 256, 0, stream>>>(
            xs_cur, rp_sn, col_sn, inv_sn, m_big, Ne);
        gemm(m_big, Wl + (size_t)H * H, bl + H, xn_nxt, Ne, H, H, 0);
        gemm(xn_cur, Wr + (size_t)H * H, nullptr, xn_nxt, Ne, H, H, F_ACC | F_RELU);

        float* t;
        t = xs_cur; xs_cur = xs_nxt; xs_nxt = t;
        t = xn_cur; xn_cur = xn_nxt; xn_nxt = t;
    }

    // ---- attentive pooling ----
    gemm(ch,     W_attc, nullptr, c_att, B,  H, H, 0);
    gemm(xs_cur, W_atts, nullptr, m_big, Ns, H, H, 0);   // s_att in m_big
    hipMemsetAsync(smax,  0, (size_t)B * 4, stream);
    hipMemsetAsync(denom, 0, (size_t)B * 4, stream);
    hipMemsetAsync(g,     0, (size_t)B * H * 4, stream);
    scores_kernel<<<(unsigned)(((long long)Ns * 64 + 255) / 256), 256, 0, stream>>>(
        m_big, c_att, batch_s, scores, smax, Ns);
    exp_kernel<<<(Ns + 255) / 256, 256, 0, stream>>>(scores, smax, batch_s, denom, Ns);
    g_kernel<<<(unsigned)(((long long)Ns * 64 + 255) / 256), 256, 0, stream>>>(
        scores, denom, batch_s, xs_cur, g, Ns);

    // ---- head MLP ----
    z_kernel<<<(B * H + 255) / 256, 256, 0, stream>>>(ch, g, z, B, H);
    gemm(z, W1, b1, hbuf, B, H, 4 * H, F_RELU);
    out_kernel<<<(B * 2 + 255) / 256, 256, 0, stream>>>(hbuf, W2, b2, (float*)d_out, B, H);
}

// Round 5
// 2466.828 us; speedup vs baseline: 3.8196x; 1.2185x over previous
//
#include <hip/hip_runtime.h>
#include <hip/hip_bf16.h>
#include <cstddef>

#define F_ACC  1
#define F_RELU 2

typedef unsigned short u16;
typedef short bf16x8 __attribute__((ext_vector_type(8)));
typedef float f32x4 __attribute__((ext_vector_type(4)));

__device__ inline u16 f2b(float x) {
    union { float f; unsigned u; } c; c.f = x;
    unsigned r = c.u + 0x7FFF + ((c.u >> 16) & 1);
    return (u16)(r >> 16);
}

// ---------------- MFMA GEMM: fp32 A (row-major [M,K]) x packed bf16 Wt ([256][K],
// n-major) -> fp32 C [M,256], flags = F_ACC / F_RELU, bias optional ----------------
#define GTM 128
#define GTN 128
#define GBK 64
#define LDA 72   // 64 + 8 pad (u16 elems), keeps 16B alignment, breaks conflicts

__global__ __launch_bounds__(256) void gemm_mfma(
    const float* __restrict__ A, const u16* __restrict__ Wt,
    const float* __restrict__ bias, float* __restrict__ C,
    int M, int K, int flags)
{
    __shared__ u16 As[GTM][LDA];
    __shared__ u16 Bs[GTN][LDA];
    const int tid  = threadIdx.x;
    const int bm   = blockIdx.x * GTM;
    const int bn   = blockIdx.y * GTN;
    const int wave = tid >> 6, lane = tid & 63;
    const int wm   = (wave >> 1) * 64, wn = (wave & 1) * 64;
    const int l16  = lane & 15, lq = lane >> 4;
    const int sr   = tid >> 1;          // 0..127
    const int sk   = (tid & 1) * 32;    // 0 or 32

    f32x4 acc[4][4] = {};

    const int  arow = bm + sr;
    const bool aok  = arow < M;
    const float* Ap = A + (size_t)(aok ? arow : 0) * K + sk;
    const u16*   Wp = Wt + (size_t)(bn + sr) * K + sk;

    for (int k0 = 0; k0 < K; k0 += GBK) {
        // ---- stage A: 32 fp32 -> bf16 ----
#pragma unroll
        for (int i = 0; i < 4; ++i) {
            float4 a, b;
            if (aok) {
                a = *(const float4*)(Ap + k0 + i * 8);
                b = *(const float4*)(Ap + k0 + i * 8 + 4);
            } else {
                a = make_float4(0.f, 0.f, 0.f, 0.f);
                b = a;
            }
            ushort4 lo, hi;
            lo.x = f2b(a.x); lo.y = f2b(a.y); lo.z = f2b(a.z); lo.w = f2b(a.w);
            hi.x = f2b(b.x); hi.y = f2b(b.y); hi.z = f2b(b.z); hi.w = f2b(b.w);
            *(ushort4*)&As[sr][sk + i * 8]     = lo;
            *(ushort4*)&As[sr][sk + i * 8 + 4] = hi;
        }
        // ---- stage B: already bf16, n-major rows ----
#pragma unroll
        for (int i = 0; i < 4; ++i)
            *(float4*)&Bs[sr][sk + i * 8] = *(const float4*)(Wp + k0 + i * 8);
        __syncthreads();
        // ---- MFMA ----
#pragma unroll
        for (int kk = 0; kk < GBK; kk += 32) {
            bf16x8 af[4], bfr[4];
#pragma unroll
            for (int mt = 0; mt < 4; ++mt)
                af[mt] = *(const bf16x8*)&As[wm + mt * 16 + l16][kk + lq * 8];
#pragma unroll
            for (int nt = 0; nt < 4; ++nt)
                bfr[nt] = *(const bf16x8*)&Bs[wn + nt * 16 + l16][kk + lq * 8];
#pragma unroll
            for (int mt = 0; mt < 4; ++mt)
#pragma unroll
                for (int nt = 0; nt < 4; ++nt)
                    acc[mt][nt] = __builtin_amdgcn_mfma_f32_16x16x32_bf16(
                        af[mt], bfr[nt], acc[mt][nt], 0, 0, 0);
        }
        __syncthreads();
    }

    // epilogue: C/D layout col=lane&15, row=(lane>>4)*4+reg
#pragma unroll
    for (int mt = 0; mt < 4; ++mt) {
#pragma unroll
        for (int nt = 0; nt < 4; ++nt) {
            int col = bn + wn + nt * 16 + l16;
            float bv = (bias != nullptr) ? bias[col] : 0.f;
#pragma unroll
            for (int r = 0; r < 4; ++r) {
                int row = bm + wm + mt * 16 + lq * 4 + r;
                if (row >= M) continue;
                float v = acc[mt][nt][r] + bv;
                size_t o = (size_t)row * 256 + col;
                if (flags & F_ACC) v += C[o];
                if (flags & F_RELU) v = fmaxf(v, 0.f);
                C[o] = v;
            }
        }
    }
}

// W [Kpart,256] fp32 (+optional addend) -> out[n][koff+k] bf16, out is [256][Ktot]
__global__ void pack_wt(const float* __restrict__ W, const float* __restrict__ Wadd,
                        u16* __restrict__ out, int Kpart, int Ktot, int koff)
{
    int idx = blockIdx.x * blockDim.x + threadIdx.x;
    if (idx >= 256 * Kpart) return;
    int n = idx / Kpart, k = idx % Kpart;
    float v = W[(size_t)k * 256 + n];
    if (Wadd) v += Wadd[(size_t)k * 256 + n];
    out[(size_t)n * Ktot + koff + k] = f2b(v);
}

__global__ void vsum_bias(const float* __restrict__ a, const float* __restrict__ b,
                          float* __restrict__ o, int n)
{
    int i = blockIdx.x * blockDim.x + threadIdx.x;
    if (i < n) o[i] = a[i] + b[i];
}

// ---------------- CSR construction ----------------

__global__ void count_edges(const int* __restrict__ dst, int E, int* __restrict__ cnt)
{
    int i = blockIdx.x * blockDim.x + threadIdx.x;
    if (i < E) atomicAdd(&cnt[dst[i]], 1);
}

__global__ void make_inv(const int* __restrict__ cnt, float* __restrict__ inv, int n)
{
    int i = blockIdx.x * blockDim.x + threadIdx.x;
    if (i < n) {
        int c = cnt[i];
        inv[i] = 1.0f / (float)(c > 1 ? c : 1);
    }
}

__global__ void scan1(const int* __restrict__ cnt, int n, int* __restrict__ rowptr,
                      int* __restrict__ bsums)
{
    __shared__ int tmp[256];
    int i = blockIdx.x * 256 + threadIdx.x;
    tmp[threadIdx.x] = (i < n) ? cnt[i] : 0;
    __syncthreads();
    for (int off = 1; off < 256; off <<= 1) {
        int t = (threadIdx.x >= (unsigned)off) ? tmp[threadIdx.x - off] : 0;
        __syncthreads();
        tmp[threadIdx.x] += t;
        __syncthreads();
    }
    if (i < n) rowptr[i + 1] = tmp[threadIdx.x];
    if (threadIdx.x == 255) bsums[blockIdx.x] = tmp[255];
}

__global__ void scan2(int* __restrict__ bsums, int nb)
{
    __shared__ int tmp[256];
    __shared__ int carry;
    if (threadIdx.x == 0) carry = 0;
    __syncthreads();
    for (int base = 0; base < nb; base += 256) {
        int i = base + threadIdx.x;
        tmp[threadIdx.x] = (i < nb) ? bsums[i] : 0;
        __syncthreads();
        for (int off = 1; off < 256; off <<= 1) {
            int t = (threadIdx.x >= (unsigned)off) ? tmp[threadIdx.x - off] : 0;
            __syncthreads();
            tmp[threadIdx.x] += t;
            __syncthreads();
        }
        int c = carry;
        if (i < nb) bsums[i] = tmp[threadIdx.x] + c;
        __syncthreads();
        if (threadIdx.x == 255) carry = c + tmp[255];
        __syncthreads();
    }
}

__global__ void scan3(int* __restrict__ rowptr, const int* __restrict__ bsums, int n)
{
    int i = blockIdx.x * 256 + threadIdx.x;
    if (i == 0) rowptr[0] = 0;
    if (i < n && blockIdx.x > 0) rowptr[i + 1] += bsums[blockIdx.x - 1];
}

__global__ void csr_fill(const int* __restrict__ src, const int* __restrict__ dst, int E,
                         const int* __restrict__ rowptr, int* __restrict__ fillc,
                         int* __restrict__ col)
{
    int e = blockIdx.x * blockDim.x + threadIdx.x;
    if (e < E) {
        int d = dst[e];
        int p = atomicAdd(&fillc[d], 1);
        col[rowptr[d] + p] = src[e];
    }
}

// ---------------- CSR mean-aggregation (gather, no atomics, fp32) ----------------
__global__ __launch_bounds__(256) void gather_mean(
    const float* __restrict__ X, const int* __restrict__ rowptr,
    const int* __restrict__ col, const float* __restrict__ inv,
    float* __restrict__ out, int Nd)
{
    long long gid = (long long)blockIdx.x * blockDim.x + threadIdx.x;
    int row = (int)(gid >> 6);
    if (row >= Nd) return;
    int c = (threadIdx.x & 63) << 2;
    int e0 = rowptr[row], e1 = rowptr[row + 1];
    float4 acc = make_float4(0.f, 0.f, 0.f, 0.f);
    for (int e = e0; e < e1; ++e) {
        int s = col[e];   // wave-uniform
        float4 v = *(const float4*)(X + (size_t)s * 256 + c);
        acc.x += v.x; acc.y += v.y; acc.z += v.z; acc.w += v.w;
    }
    float sc = inv[row];
    acc.x *= sc; acc.y *= sc; acc.z *= sc; acc.w *= sc;
    *(float4*)(out + (size_t)row * 256 + c) = acc;
}

// ---------------- attention / head (fp32, as round 2) ----------------

__global__ __launch_bounds__(256) void scores_kernel(
    const float* __restrict__ s_att, const float* __restrict__ c_att,
    const int* __restrict__ batch, float* __restrict__ scores,
    unsigned int* __restrict__ smax, int Ns)
{
    long long gid = (long long)blockIdx.x * blockDim.x + threadIdx.x;
    int row = (int)(gid >> 6);
    if (row >= Ns) return;
    int lane = threadIdx.x & 63;
    int b = batch[row];
    float4 s4 = *(const float4*)(s_att + (size_t)row * 256 + (lane << 2));
    float4 c4 = *(const float4*)(c_att + (size_t)b * 256 + (lane << 2));
    float p = s4.x * c4.x + s4.y * c4.y + s4.z * c4.z + s4.w * c4.w;
#pragma unroll
    for (int off = 32; off > 0; off >>= 1) p += __shfl_down(p, off, 64);
    if (lane == 0) {
        scores[row] = p;
        unsigned bits = __float_as_uint(p);
        unsigned key = (bits & 0x80000000u) ? ~bits : (bits | 0x80000000u);
        atomicMax(&smax[b], key);
    }
}

__global__ void exp_kernel(float* __restrict__ scores, const unsigned int* __restrict__ smax,
                           const int* __restrict__ batch, float* __restrict__ denom, int Ns)
{
    int i = blockIdx.x * blockDim.x + threadIdx.x;
    if (i >= Ns) return;
    int b = batch[i];
    unsigned u = smax[b];
    unsigned bits = (u & 0x80000000u) ? (u & 0x7fffffffu) : ~u;
    float mx = __uint_as_float(bits);
    float e = expf(scores[i] - mx);
    scores[i] = e;
    atomicAdd(&denom[b], e);
}

__global__ __launch_bounds__(256) void g_kernel(
    const float* __restrict__ e, const float* __restrict__ denom,
    const int* __restrict__ batch, const float* __restrict__ xs,
    float* __restrict__ g, int Ns)
{
    long long gid = (long long)blockIdx.x * blockDim.x + threadIdx.x;
    int row = (int)(gid >> 6);
    if (row >= Ns) return;
    int lane = threadIdx.x & 63;
    int b = batch[row];
    float alpha = e[row] / denom[b];
    float4 x4 = *(const float4*)(xs + (size_t)row * 256 + (lane << 2));
    float* gp = g + (size_t)b * 256 + (lane << 2);
    atomicAdd(gp + 0, alpha * x4.x); atomicAdd(gp + 1, alpha * x4.y);
    atomicAdd(gp + 2, alpha * x4.z); atomicAdd(gp + 3, alpha * x4.w);
}

__global__ void z_kernel(const float* __restrict__ ch, const float* __restrict__ g,
                         float* __restrict__ z, int B, int H)
{
    int i = blockIdx.x * blockDim.x + threadIdx.x;
    if (i >= B * H) return;
    int b = i / H, c = i % H;
    float cv = ch[i], gv = g[i];
    float* zr = z + (size_t)b * 4 * H;
    zr[c]         = cv;
    zr[H + c]     = gv;
    zr[2 * H + c] = fabsf(cv - gv);
    zr[3 * H + c] = cv * gv;
}

__global__ void out_kernel(const float* __restrict__ h, const float* __restrict__ W2,
                           const float* __restrict__ b2, float* __restrict__ out, int B, int H)
{
    int i = blockIdx.x * blockDim.x + threadIdx.x;
    if (i >= B * 2) return;
    int b = i >> 1, j = i & 1;
    float s = b2[j];
    const float* hr = h + (size_t)b * H;
    for (int k = 0; k < H; ++k) s += hr[k] * W2[k * 2 + j];
    out[i] = s;
}

extern "C" void kernel_launch(void* const* d_in, const int* in_sizes, int n_in,
                              void* d_out, int out_size, void* d_ws, size_t ws_size,
                              hipStream_t stream)
{
    const float* x_s    = (const float*)d_in[0];
    const float* x_n    = (const float*)d_in[1];
    const float* claim  = (const float*)d_in[2];
    const int*   batch_s= (const int*)d_in[3];
    const int*   src_ss = (const int*)d_in[4];
    const int*   dst_ss = (const int*)d_in[5];
    const int*   src_sn = (const int*)d_in[6];
    const int*   dst_sn = (const int*)d_in[7];
    const int*   src_ns = (const int*)d_in[8];
    const int*   dst_ns = (const int*)d_in[9];
    const float* W_ps   = (const float*)d_in[10];
    const float* b_ps   = (const float*)d_in[11];
    const float* W_pn   = (const float*)d_in[12];
    const float* b_pn   = (const float*)d_in[13];
    const float* W_pc   = (const float*)d_in[14];
    const float* b_pc   = (const float*)d_in[15];
    const float* conv_Wl= (const float*)d_in[16];
    const float* conv_bl= (const float*)d_in[17];
    const float* conv_Wr= (const float*)d_in[18];
    const float* W_attc = (const float*)d_in[19];
    const float* W_atts = (const float*)d_in[20];
    const float* W1     = (const float*)d_in[21];
    const float* b1     = (const float*)d_in[22];
    const float* W2     = (const float*)d_in[23];
    const float* b2     = (const float*)d_in[24];

    const int in_dim = 768, H = 256;
    const int Ns  = in_sizes[0] / in_dim;
    const int Ne  = in_sizes[1] / in_dim;
    const int B   = in_sizes[2] / in_dim;
    const int Ess = in_sizes[4];
    const int Esn = in_sizes[6];
    const int Ens = in_sizes[8];
    const int L   = in_sizes[16] / (3 * H * H);
    const int Nmax = (Ns > Ne) ? Ns : Ne;
    const int nb_max = (Nmax + 255) / 256;
    const size_t HH = (size_t)H * H;

    float* ws = (float*)d_ws;
    size_t off = 0;
    auto alloc = [&](size_t n) { float* p = ws + off; off += (n + 63) & ~(size_t)63; return p; };
    float* xs_a  = alloc((size_t)Ns * H);
    float* xs_b  = alloc((size_t)Ns * H);
    float* xn_a  = alloc((size_t)Ne * H);
    float* xn_b  = alloc((size_t)Ne * H);
    float* m_big = alloc((size_t)Nmax * H);   // gather output / s_att at the end
    float* ch    = alloc((size_t)B * H);
    float* c_att = alloc((size_t)B * H);
    float* bsum0 = alloc(H);
    float* bsum1 = alloc(H);
    // packed bf16 weights (u16, [256][K] n-major); sizes in float-slots = elems/2
    u16* wt_ps   = (u16*)alloc((size_t)256 * 768 / 2);
    u16* wt_pn   = (u16*)alloc((size_t)256 * 768 / 2);
    u16* wt_pc   = (u16*)alloc((size_t)256 * 768 / 2);
    u16* wt_l0_a = (u16*)alloc(HH / 2);
    u16* wt_l1_a = (u16*)alloc(HH / 2);
    u16* wt_l2_a = (u16*)alloc(HH / 2);
    u16* wt_rs_a = (u16*)alloc(HH / 2);
    u16* wt_r1_a = (u16*)alloc(HH / 2);
    u16* wt_l0_b = (u16*)alloc(HH / 2);
    u16* wt_l1_b = (u16*)alloc(HH / 2);
    u16* wt_l2_b = (u16*)alloc(HH / 2);
    u16* wt_rs_b = (u16*)alloc(HH / 2);
    u16* wt_r1_b = (u16*)alloc(HH / 2);
    u16* wt_atts = (u16*)alloc(HH / 2);
    u16* wt_attc = (u16*)alloc(HH / 2);
    u16* wt_w1   = (u16*)alloc((size_t)256 * 1024 / 2);
    // CSR
    int*   cnt_ss = (int*)alloc(Ns);
    int*   cnt_sn = (int*)alloc(Ne);
    int*   cnt_ns = (int*)alloc(Ns);
    float* inv_ss = alloc(Ns);
    float* inv_sn = alloc(Ne);
    float* inv_ns = alloc(Ns);
    int*   rp_ss  = (int*)alloc(Ns + 1);
    int*   rp_sn  = (int*)alloc(Ne + 1);
    int*   rp_ns  = (int*)alloc(Ns + 1);
    int*   col_ss = (int*)alloc(Ess);
    int*   col_sn = (int*)alloc(Esn);
    int*   col_ns = (int*)alloc(Ens);
    int*   fillc  = (int*)alloc(Nmax);
    int*   bsums  = (int*)alloc(nb_max);
    // attention / head
    float* scores = alloc(Ns);
    unsigned int* smax = (unsigned int*)alloc(B);
    float* denom = alloc(B);
    float* g     = alloc((size_t)B * H);
    float* z     = alloc((size_t)B * 4 * H);
    float* hbuf  = alloc((size_t)B * H);
    (void)ws_size; (void)n_in; (void)out_size;

    auto gemm = [&](const float* A, const u16* Wt, const float* bias,
                    float* C, int M, int K, int flags) {
        dim3 grid((M + GTM - 1) / GTM, 2);
        gemm_mfma<<<grid, dim3(256), 0, stream>>>(A, Wt, bias, C, M, K, flags);
    };
    auto pack = [&](const float* W, const float* Wadd, u16* o, int Kpart) {
        pack_wt<<<(256 * Kpart + 255) / 256, 256, 0, stream>>>(W, Wadd, o, Kpart, Kpart, 0);
    };

    // ---- weight packing ----
    pack(W_ps, nullptr, wt_ps, 768);
    pack(W_pn, nullptr, wt_pn, 768);
    pack(W_pc, nullptr, wt_pc, 768);
    u16* wt_l0[2] = {wt_l0_a, wt_l0_b};
    u16* wt_l1[2] = {wt_l1_a, wt_l1_b};
    u16* wt_l2[2] = {wt_l2_a, wt_l2_b};
    u16* wt_rs[2] = {wt_rs_a, wt_rs_b};
    u16* wt_r1[2] = {wt_r1_a, wt_r1_b};
    float* bsum[2] = {bsum0, bsum1};
    for (int l = 0; l < L; ++l) {
        const float* Wl = conv_Wl + (size_t)l * 3 * HH;
        const float* bl = conv_bl + (size_t)l * 3 * H;
        const float* Wr = conv_Wr + (size_t)l * 3 * HH;
        pack(Wl,          nullptr,     wt_l0[l], 256);   // Wl_ss
        pack(Wl + HH,     nullptr,     wt_l1[l], 256);   // Wl_sn
        pack(Wl + 2 * HH, nullptr,     wt_l2[l], 256);   // Wl_ns
        pack(Wr,          Wr + 2 * HH, wt_rs[l], 256);   // Wr_ss + Wr_ns
        pack(Wr + HH,     nullptr,     wt_r1[l], 256);   // Wr_sn
        vsum_bias<<<1, 256, 0, stream>>>(bl, bl + 2 * H, bsum[l], H);
    }
    pack(W_atts, nullptr, wt_atts, 256);
    pack(W_attc, nullptr, wt_attc, 256);
    pack(W1,     nullptr, wt_w1, 1024);

    // ---- degree counts + CSR ----
    hipMemsetAsync(cnt_ss, 0, (size_t)Ns * 4, stream);
    hipMemsetAsync(cnt_sn, 0, (size_t)Ne * 4, stream);
    hipMemsetAsync(cnt_ns, 0, (size_t)Ns * 4, stream);
    count_edges<<<(Ess + 255) / 256, 256, 0, stream>>>(dst_ss, Ess, cnt_ss);
    count_edges<<<(Esn + 255) / 256, 256, 0, stream>>>(dst_sn, Esn, cnt_sn);
    count_edges<<<(Ens + 255) / 256, 256, 0, stream>>>(dst_ns, Ens, cnt_ns);
    make_inv<<<(Ns + 255) / 256, 256, 0, stream>>>(cnt_ss, inv_ss, Ns);
    make_inv<<<(Ne + 255) / 256, 256, 0, stream>>>(cnt_sn, inv_sn, Ne);
    make_inv<<<(Ns + 255) / 256, 256, 0, stream>>>(cnt_ns, inv_ns, Ns);
    auto build_csr = [&](const int* src, const int* dst, int E, int Nd,
                         const int* cnt, int* rowptr, int* colidx) {
        int nb = (Nd + 255) / 256;
        scan1<<<nb, 256, 0, stream>>>(cnt, Nd, rowptr, bsums);
        scan2<<<1, 256, 0, stream>>>(bsums, nb);
        scan3<<<nb, 256, 0, stream>>>(rowptr, bsums, Nd);
        hipMemsetAsync(fillc, 0, (size_t)Nd * 4, stream);
        csr_fill<<<(E + 255) / 256, 256, 0, stream>>>(src, dst, E, rowptr, fillc, colidx);
    };
    build_csr(src_ss, dst_ss, Ess, Ns, cnt_ss, rp_ss, col_ss);
    build_csr(src_sn, dst_sn, Esn, Ne, cnt_sn, rp_sn, col_sn);
    build_csr(src_ns, dst_ns, Ens, Ns, cnt_ns, rp_ns, col_ns);

    // ---- input projections ----
    gemm(x_s,   wt_ps, b_ps, xs_a, Ns, 768, F_RELU);
    gemm(x_n,   wt_pn, b_pn, xn_a, Ne, 768, F_RELU);
    gemm(claim, wt_pc, b_pc, ch,   B,  768, F_RELU);

    // ---- GNN layers (same sequence as round 2) ----
    float* xs_cur = xs_a; float* xs_nxt = xs_b;
    float* xn_cur = xn_a; float* xn_nxt = xn_b;
    for (int l = 0; l < L; ++l) {
        const float* bl = conv_bl + (size_t)l * 3 * H;

        gather_mean<<<(unsigned)(((long long)Ns * 64 + 255) / 256), 256, 0, stream>>>(
            xs_cur, rp_ss, col_ss, inv_ss, m_big, Ns);
        gemm(m_big, wt_l0[l], bsum[l], xs_nxt, Ns, 256, 0);

        gather_mean<<<(unsigned)(((long long)Ns * 64 + 255) / 256), 256, 0, stream>>>(
            xn_cur, rp_ns, col_ns, inv_ns, m_big, Ns);
        gemm(m_big, wt_l2[l], nullptr, xs_nxt, Ns, 256, F_ACC);

        gemm(xs_cur, wt_rs[l], nullptr, xs_nxt, Ns, 256, F_ACC | F_RELU);

        gather_mean<<<(unsigned)(((long long)Ne * 64 + 255) / 256), 256, 0, stream>>>(
            xs_cur, rp_sn, col_sn, inv_sn, m_big, Ne);
        gemm(m_big, wt_l1[l], bl + H, xn_nxt, Ne, 256, 0);
        gemm(xn_cur, wt_r1[l], nullptr, xn_nxt, Ne, 256, F_ACC | F_RELU);

        float* t;
        t = xs_cur; xs_cur = xs_nxt; xs_nxt = t;
        t = xn_cur; xn_cur = xn_nxt; xn_nxt = t;
    }

    // ---- attentive pooling ----
    gemm(ch,     wt_attc, nullptr, c_att, B,  256, 0);
    gemm(xs_cur, wt_atts, nullptr, m_big, Ns, 256, 0);   // s_att in m_big
    hipMemsetAsync(smax,  0, (size_t)B * 4, stream);
    hipMemsetAsync(denom, 0, (size_t)B * 4, stream);
    hipMemsetAsync(g,     0, (size_t)B * H * 4, stream);
    scores_kernel<<<(unsigned)(((long long)Ns * 64 + 255) / 256), 256, 0, stream>>>(
        m_big, c_att, batch_s, scores, smax, Ns);
    exp_kernel<<<(Ns + 255) / 256, 256, 0, stream>>>(scores, smax, batch_s, denom, Ns);
    g_kernel<<<(unsigned)(((long long)Ns * 64 + 255) / 256), 256, 0, stream>>>(
        scores, denom, batch_s, xs_cur, g, Ns);

    // ---- head MLP ----
    z_kernel<<<(B * H + 255) / 256, 256, 0, stream>>>(ch, g, z, B, H);
    gemm(z, wt_w1, b1, hbuf, B, 1024, F_RELU);
    out_kernel<<<(B * 2 + 255) / 256, 256, 0, stream>>>(hbuf, W2, b2, (float*)d_out, B, 256);
}

// Round 6
// 1868.791 us; speedup vs baseline: 5.0419x; 1.3200x over previous
//
#include <hip/hip_runtime.h>
#include <hip/hip_bf16.h>
#include <cstddef>

#define F_ACC  1
#define F_RELU 2

typedef unsigned short u16;
typedef short bf16x8 __attribute__((ext_vector_type(8)));
typedef float f32x4 __attribute__((ext_vector_type(4)));

__device__ inline u16 f2b(float x) {
    union { float f; unsigned u; } c; c.f = x;
    unsigned r = c.u + 0x7FFF + ((c.u >> 16) & 1);
    return (u16)(r >> 16);
}

// ---------------- MFMA GEMM: fp32 A (row-major [M,K]) x packed bf16 Wt ([256][K],
// n-major) -> fp32 C [M,256], flags = F_ACC / F_RELU, bias optional ----------------
#define GTM 128
#define GTN 128
#define GBK 64
#define LDA 72   // 64 + 8 pad (u16 elems), keeps 16B alignment, breaks conflicts

__global__ __launch_bounds__(256) void gemm_mfma(
    const float* __restrict__ A, const u16* __restrict__ Wt,
    const float* __restrict__ bias, float* __restrict__ C,
    int M, int K, int flags)
{
    __shared__ u16 As[GTM][LDA];
    __shared__ u16 Bs[GTN][LDA];
    const int tid  = threadIdx.x;
    const int bm   = blockIdx.x * GTM;
    const int bn   = blockIdx.y * GTN;
    const int wave = tid >> 6, lane = tid & 63;
    const int wm   = (wave >> 1) * 64, wn = (wave & 1) * 64;
    const int l16  = lane & 15, lq = lane >> 4;
    const int sr   = tid >> 1;          // 0..127
    const int sk   = (tid & 1) * 32;    // 0 or 32

    f32x4 acc[4][4] = {};

    const int  arow = bm + sr;
    const bool aok  = arow < M;
    const float* Ap = A + (size_t)(aok ? arow : 0) * K + sk;
    const u16*   Wp = Wt + (size_t)(bn + sr) * K + sk;

    for (int k0 = 0; k0 < K; k0 += GBK) {
        // ---- stage A: 32 fp32 -> bf16 ----
#pragma unroll
        for (int i = 0; i < 4; ++i) {
            float4 a, b;
            if (aok) {
                a = *(const float4*)(Ap + k0 + i * 8);
                b = *(const float4*)(Ap + k0 + i * 8 + 4);
            } else {
                a = make_float4(0.f, 0.f, 0.f, 0.f);
                b = a;
            }
            ushort4 lo, hi;
            lo.x = f2b(a.x); lo.y = f2b(a.y); lo.z = f2b(a.z); lo.w = f2b(a.w);
            hi.x = f2b(b.x); hi.y = f2b(b.y); hi.z = f2b(b.z); hi.w = f2b(b.w);
            *(ushort4*)&As[sr][sk + i * 8]     = lo;
            *(ushort4*)&As[sr][sk + i * 8 + 4] = hi;
        }
        // ---- stage B: already bf16, n-major rows ----
#pragma unroll
        for (int i = 0; i < 4; ++i)
            *(float4*)&Bs[sr][sk + i * 8] = *(const float4*)(Wp + k0 + i * 8);
        __syncthreads();
        // ---- MFMA ----
#pragma unroll
        for (int kk = 0; kk < GBK; kk += 32) {
            bf16x8 af[4], bfr[4];
#pragma unroll
            for (int mt = 0; mt < 4; ++mt)
                af[mt] = *(const bf16x8*)&As[wm + mt * 16 + l16][kk + lq * 8];
#pragma unroll
            for (int nt = 0; nt < 4; ++nt)
                bfr[nt] = *(const bf16x8*)&Bs[wn + nt * 16 + l16][kk + lq * 8];
#pragma unroll
            for (int mt = 0; mt < 4; ++mt)
#pragma unroll
                for (int nt = 0; nt < 4; ++nt)
                    acc[mt][nt] = __builtin_amdgcn_mfma_f32_16x16x32_bf16(
                        af[mt], bfr[nt], acc[mt][nt], 0, 0, 0);
        }
        __syncthreads();
    }

    // epilogue: C/D layout col=lane&15, row=(lane>>4)*4+reg
#pragma unroll
    for (int mt = 0; mt < 4; ++mt) {
#pragma unroll
        for (int nt = 0; nt < 4; ++nt) {
            int col = bn + wn + nt * 16 + l16;
            float bv = (bias != nullptr) ? bias[col] : 0.f;
#pragma unroll
            for (int r = 0; r < 4; ++r) {
                int row = bm + wm + mt * 16 + lq * 4 + r;
                if (row >= M) continue;
                float v = acc[mt][nt][r] + bv;
                size_t o = (size_t)row * 256 + col;
                if (flags & F_ACC) v += C[o];
                if (flags & F_RELU) v = fmaxf(v, 0.f);
                C[o] = v;
            }
        }
    }
}

// W [Kpart,256] fp32 (+optional addend) -> out[n][koff+k] bf16, out is [256][Ktot]
__global__ void pack_wt(const float* __restrict__ W, const float* __restrict__ Wadd,
                        u16* __restrict__ out, int Kpart, int Ktot, int koff)
{
    int idx = blockIdx.x * blockDim.x + threadIdx.x;
    if (idx >= 256 * Kpart) return;
    int n = idx / Kpart, k = idx % Kpart;
    float v = W[(size_t)k * 256 + n];
    if (Wadd) v += Wadd[(size_t)k * 256 + n];
    out[(size_t)n * Ktot + koff + k] = f2b(v);
}

__global__ void vsum_bias(const float* __restrict__ a, const float* __restrict__ b,
                          float* __restrict__ o, int n)
{
    int i = blockIdx.x * blockDim.x + threadIdx.x;
    if (i < n) o[i] = a[i] + b[i];
}

// ---------------- CSR construction ----------------

__global__ void count_edges(const int* __restrict__ dst, int E, int* __restrict__ cnt)
{
    int i = blockIdx.x * blockDim.x + threadIdx.x;
    if (i < E) atomicAdd(&cnt[dst[i]], 1);
}

__global__ void make_inv(const int* __restrict__ cnt, float* __restrict__ inv, int n)
{
    int i = blockIdx.x * blockDim.x + threadIdx.x;
    if (i < n) {
        int c = cnt[i];
        inv[i] = 1.0f / (float)(c > 1 ? c : 1);
    }
}

__global__ void scan1(const int* __restrict__ cnt, int n, int* __restrict__ rowptr,
                      int* __restrict__ bsums)
{
    __shared__ int tmp[256];
    int i = blockIdx.x * 256 + threadIdx.x;
    tmp[threadIdx.x] = (i < n) ? cnt[i] : 0;
    __syncthreads();
    for (int off = 1; off < 256; off <<= 1) {
        int t = (threadIdx.x >= (unsigned)off) ? tmp[threadIdx.x - off] : 0;
        __syncthreads();
        tmp[threadIdx.x] += t;
        __syncthreads();
    }
    if (i < n) rowptr[i + 1] = tmp[threadIdx.x];
    if (threadIdx.x == 255) bsums[blockIdx.x] = tmp[255];
}

__global__ void scan2(int* __restrict__ bsums, int nb)
{
    __shared__ int tmp[256];
    __shared__ int carry;
    if (threadIdx.x == 0) carry = 0;
    __syncthreads();
    for (int base = 0; base < nb; base += 256) {
        int i = base + threadIdx.x;
        tmp[threadIdx.x] = (i < nb) ? bsums[i] : 0;
        __syncthreads();
        for (int off = 1; off < 256; off <<= 1) {
            int t = (threadIdx.x >= (unsigned)off) ? tmp[threadIdx.x - off] : 0;
            __syncthreads();
            tmp[threadIdx.x] += t;
            __syncthreads();
        }
        int c = carry;
        if (i < nb) bsums[i] = tmp[threadIdx.x] + c;
        __syncthreads();
        if (threadIdx.x == 255) carry = c + tmp[255];
        __syncthreads();
    }
}

__global__ void scan3(int* __restrict__ rowptr, const int* __restrict__ bsums, int n)
{
    int i = blockIdx.x * 256 + threadIdx.x;
    if (i == 0) rowptr[0] = 0;
    if (i < n && blockIdx.x > 0) rowptr[i + 1] += bsums[blockIdx.x - 1];
}

__global__ void csr_fill(const int* __restrict__ src, const int* __restrict__ dst, int E,
                         const int* __restrict__ rowptr, int* __restrict__ fillc,
                         int* __restrict__ col)
{
    int e = blockIdx.x * blockDim.x + threadIdx.x;
    if (e < E) {
        int d = dst[e];
        int p = atomicAdd(&fillc[d], 1);
        col[rowptr[d] + p] = src[e];
    }
}

// ---------------- CSR mean-aggregation (gather, no atomics, fp32) ----------------
__global__ __launch_bounds__(256) void gather_mean(
    const float* __restrict__ X, const int* __restrict__ rowptr,
    const int* __restrict__ col, const float* __restrict__ inv,
    float* __restrict__ out, int Nd)
{
    long long gid = (long long)blockIdx.x * blockDim.x + threadIdx.x;
    int row = (int)(gid >> 6);
    if (row >= Nd) return;
    int c = (threadIdx.x & 63) << 2;
    int e0 = rowptr[row], e1 = rowptr[row + 1];
    float4 acc = make_float4(0.f, 0.f, 0.f, 0.f);
    int e = e0;
    for (; e + 1 < e1; e += 2) {           // 2-way unroll: independent loads
        int s0 = col[e], s1 = col[e + 1];  // wave-uniform
        float4 v0 = *(const float4*)(X + (size_t)s0 * 256 + c);
        float4 v1 = *(const float4*)(X + (size_t)s1 * 256 + c);
        acc.x += v0.x + v1.x; acc.y += v0.y + v1.y;
        acc.z += v0.z + v1.z; acc.w += v0.w + v1.w;
    }
    if (e < e1) {
        int s = col[e];
        float4 v = *(const float4*)(X + (size_t)s * 256 + c);
        acc.x += v.x; acc.y += v.y; acc.z += v.z; acc.w += v.w;
    }
    float sc = inv[row];
    acc.x *= sc; acc.y *= sc; acc.z *= sc; acc.w *= sc;
    *(float4*)(out + (size_t)row * 256 + c) = acc;
}

// ---------------- attention / pooling (segmented, no atomics) ----------------

// scores[i] = dot(s_att[i,:], c_att[batch[i],:]) — one wave per row
__global__ __launch_bounds__(256) void scores_kernel(
    const float* __restrict__ s_att, const float* __restrict__ c_att,
    const int* __restrict__ batch, float* __restrict__ scores, int Ns)
{
    long long gid = (long long)blockIdx.x * blockDim.x + threadIdx.x;
    int row = (int)(gid >> 6);
    if (row >= Ns) return;
    int lane = threadIdx.x & 63;
    int b = batch[row];
    float4 s4 = *(const float4*)(s_att + (size_t)row * 256 + (lane << 2));
    float4 c4 = *(const float4*)(c_att + (size_t)b * 256 + (lane << 2));
    float p = s4.x * c4.x + s4.y * c4.y + s4.z * c4.z + s4.w * c4.w;
#pragma unroll
    for (int off = 32; off > 0; off >>= 1) p += __shfl_down(p, off, 64);
    if (lane == 0) scores[row] = p;
}

// batch_s is sorted: rp[b] = first row with batch >= b; rp[B] = Ns
__global__ void batch_bounds(const int* __restrict__ batch, int Ns, int B,
                             int* __restrict__ rp)
{
    int i = blockIdx.x * blockDim.x + threadIdx.x;
    if (i > Ns) return;
    if (i == 0) {
        int b1 = batch[0];
        for (int b = 0; b <= b1; ++b) rp[b] = 0;
    } else if (i == Ns) {
        int b0 = batch[Ns - 1];
        for (int b = b0 + 1; b <= B; ++b) rp[b] = Ns;
    } else {
        int b0 = batch[i - 1], b1 = batch[i];
        for (int b = b0 + 1; b <= b1; ++b) rp[b] = i;
    }
}

// one block per graph: softmax over its contiguous rows + weighted column sum
// scores is overwritten with exp(score - max) as scratch
__global__ __launch_bounds__(256) void pool_kernel(
    float* __restrict__ scores, const float* __restrict__ xs,
    const int* __restrict__ rp, float* __restrict__ g)
{
    __shared__ float red[256];
    const int b = blockIdx.x, tid = threadIdx.x;
    const int r0 = rp[b], r1 = rp[b + 1];
    if (r0 >= r1) { g[(size_t)b * 256 + tid] = 0.f; return; }  // uniform per block
    // phase 1: max
    float m = -3.4e38f;
    for (int r = r0 + tid; r < r1; r += 256) m = fmaxf(m, scores[r]);
    red[tid] = m; __syncthreads();
    for (int s = 128; s > 0; s >>= 1) {
        if (tid < s) red[tid] = fmaxf(red[tid], red[tid + s]);
        __syncthreads();
    }
    m = red[0]; __syncthreads();
    // phase 2: exp + sum (each thread owns its strided rows; write e in place)
    float sum = 0.f;
    for (int r = r0 + tid; r < r1; r += 256) {
        float e = __expf(scores[r] - m);
        scores[r] = e;
        sum += e;
    }
    red[tid] = sum; __syncthreads();
    for (int s = 128; s > 0; s >>= 1) {
        if (tid < s) red[tid] += red[tid + s];
        __syncthreads();
    }
    const float inv = 1.0f / red[0];
    __syncthreads();
    // phase 3: column accumulation, thread = column
    float acc = 0.f;
    for (int r = r0; r < r1; ++r)
        acc += scores[r] * xs[(size_t)r * 256 + tid];
    g[(size_t)b * 256 + tid] = acc * inv;
}

__global__ void z_kernel(const float* __restrict__ ch, const float* __restrict__ g,
                         float* __restrict__ z, int B, int H)
{
    int i = blockIdx.x * blockDim.x + threadIdx.x;
    if (i >= B * H) return;
    int b = i / H, c = i % H;
    float cv = ch[i], gv = g[i];
    float* zr = z + (size_t)b * 4 * H;
    zr[c]         = cv;
    zr[H + c]     = gv;
    zr[2 * H + c] = fabsf(cv - gv);
    zr[3 * H + c] = cv * gv;
}

__global__ void out_kernel(const float* __restrict__ h, const float* __restrict__ W2,
                           const float* __restrict__ b2, float* __restrict__ out, int B, int H)
{
    int i = blockIdx.x * blockDim.x + threadIdx.x;
    if (i >= B * 2) return;
    int b = i >> 1, j = i & 1;
    float s = b2[j];
    const float* hr = h + (size_t)b * H;
    for (int k = 0; k < H; ++k) s += hr[k] * W2[k * 2 + j];
    out[i] = s;
}

extern "C" void kernel_launch(void* const* d_in, const int* in_sizes, int n_in,
                              void* d_out, int out_size, void* d_ws, size_t ws_size,
                              hipStream_t stream)
{
    const float* x_s    = (const float*)d_in[0];
    const float* x_n    = (const float*)d_in[1];
    const float* claim  = (const float*)d_in[2];
    const int*   batch_s= (const int*)d_in[3];
    const int*   src_ss = (const int*)d_in[4];
    const int*   dst_ss = (const int*)d_in[5];
    const int*   src_sn = (const int*)d_in[6];
    const int*   dst_sn = (const int*)d_in[7];
    const int*   src_ns = (const int*)d_in[8];
    const int*   dst_ns = (const int*)d_in[9];
    const float* W_ps   = (const float*)d_in[10];
    const float* b_ps   = (const float*)d_in[11];
    const float* W_pn   = (const float*)d_in[12];
    const float* b_pn   = (const float*)d_in[13];
    const float* W_pc   = (const float*)d_in[14];
    const float* b_pc   = (const float*)d_in[15];
    const float* conv_Wl= (const float*)d_in[16];
    const float* conv_bl= (const float*)d_in[17];
    const float* conv_Wr= (const float*)d_in[18];
    const float* W_attc = (const float*)d_in[19];
    const float* W_atts = (const float*)d_in[20];
    const float* W1     = (const float*)d_in[21];
    const float* b1     = (const float*)d_in[22];
    const float* W2     = (const float*)d_in[23];
    const float* b2     = (const float*)d_in[24];

    const int in_dim = 768, H = 256;
    const int Ns  = in_sizes[0] / in_dim;
    const int Ne  = in_sizes[1] / in_dim;
    const int B   = in_sizes[2] / in_dim;
    const int Ess = in_sizes[4];
    const int Esn = in_sizes[6];
    const int Ens = in_sizes[8];
    const int L   = in_sizes[16] / (3 * H * H);
    const int Nmax = (Ns > Ne) ? Ns : Ne;
    const int nb_max = (Nmax + 255) / 256;
    const size_t HH = (size_t)H * H;

    float* ws = (float*)d_ws;
    size_t off = 0;
    auto alloc = [&](size_t n) { float* p = ws + off; off += (n + 63) & ~(size_t)63; return p; };
    float* xs_a  = alloc((size_t)Ns * H);
    float* xs_b  = alloc((size_t)Ns * H);
    float* xn_a  = alloc((size_t)Ne * H);
    float* xn_b  = alloc((size_t)Ne * H);
    float* m_big = alloc((size_t)Nmax * H);   // gather output / s_att at the end
    float* ch    = alloc((size_t)B * H);
    float* c_att = alloc((size_t)B * H);
    float* bsum0 = alloc(H);
    float* bsum1 = alloc(H);
    // packed bf16 weights (u16, [256][K] n-major); sizes in float-slots = elems/2
    u16* wt_ps   = (u16*)alloc((size_t)256 * 768 / 2);
    u16* wt_pn   = (u16*)alloc((size_t)256 * 768 / 2);
    u16* wt_pc   = (u16*)alloc((size_t)256 * 768 / 2);
    u16* wt_l0_a = (u16*)alloc(HH / 2);
    u16* wt_l1_a = (u16*)alloc(HH / 2);
    u16* wt_l2_a = (u16*)alloc(HH / 2);
    u16* wt_rs_a = (u16*)alloc(HH / 2);
    u16* wt_r1_a = (u16*)alloc(HH / 2);
    u16* wt_l0_b = (u16*)alloc(HH / 2);
    u16* wt_l1_b = (u16*)alloc(HH / 2);
    u16* wt_l2_b = (u16*)alloc(HH / 2);
    u16* wt_rs_b = (u16*)alloc(HH / 2);
    u16* wt_r1_b = (u16*)alloc(HH / 2);
    u16* wt_atts = (u16*)alloc(HH / 2);
    u16* wt_attc = (u16*)alloc(HH / 2);
    u16* wt_w1   = (u16*)alloc((size_t)256 * 1024 / 2);
    // CSR
    int*   cnt_ss = (int*)alloc(Ns);
    int*   cnt_sn = (int*)alloc(Ne);
    int*   cnt_ns = (int*)alloc(Ns);
    float* inv_ss = alloc(Ns);
    float* inv_sn = alloc(Ne);
    float* inv_ns = alloc(Ns);
    int*   rp_ss  = (int*)alloc(Ns + 1);
    int*   rp_sn  = (int*)alloc(Ne + 1);
    int*   rp_ns  = (int*)alloc(Ns + 1);
    int*   col_ss = (int*)alloc(Ess);
    int*   col_sn = (int*)alloc(Esn);
    int*   col_ns = (int*)alloc(Ens);
    int*   fillc  = (int*)alloc(Nmax);
    int*   bsums  = (int*)alloc(nb_max);
    // attention / head
    float* scores = alloc(Ns);
    int*   rp_b   = (int*)alloc(B + 1);
    float* g      = alloc((size_t)B * H);
    float* z      = alloc((size_t)B * 4 * H);
    float* hbuf   = alloc((size_t)B * H);
    (void)ws_size; (void)n_in; (void)out_size;

    auto gemm = [&](const float* A, const u16* Wt, const float* bias,
                    float* C, int M, int K, int flags) {
        dim3 grid((M + GTM - 1) / GTM, 2);
        gemm_mfma<<<grid, dim3(256), 0, stream>>>(A, Wt, bias, C, M, K, flags);
    };
    auto pack = [&](const float* W, const float* Wadd, u16* o, int Kpart) {
        pack_wt<<<(256 * Kpart + 255) / 256, 256, 0, stream>>>(W, Wadd, o, Kpart, Kpart, 0);
    };

    // ---- weight packing ----
    pack(W_ps, nullptr, wt_ps, 768);
    pack(W_pn, nullptr, wt_pn, 768);
    pack(W_pc, nullptr, wt_pc, 768);
    u16* wt_l0[2] = {wt_l0_a, wt_l0_b};
    u16* wt_l1[2] = {wt_l1_a, wt_l1_b};
    u16* wt_l2[2] = {wt_l2_a, wt_l2_b};
    u16* wt_rs[2] = {wt_rs_a, wt_rs_b};
    u16* wt_r1[2] = {wt_r1_a, wt_r1_b};
    float* bsum[2] = {bsum0, bsum1};
    for (int l = 0; l < L; ++l) {
        const float* Wl = conv_Wl + (size_t)l * 3 * HH;
        const float* bl = conv_bl + (size_t)l * 3 * H;
        const float* Wr = conv_Wr + (size_t)l * 3 * HH;
        pack(Wl,          nullptr,     wt_l0[l], 256);   // Wl_ss
        pack(Wl + HH,     nullptr,     wt_l1[l], 256);   // Wl_sn
        pack(Wl + 2 * HH, nullptr,     wt_l2[l], 256);   // Wl_ns
        pack(Wr,          Wr + 2 * HH, wt_rs[l], 256);   // Wr_ss + Wr_ns
        pack(Wr + HH,     nullptr,     wt_r1[l], 256);   // Wr_sn
        vsum_bias<<<1, 256, 0, stream>>>(bl, bl + 2 * H, bsum[l], H);
    }
    pack(W_atts, nullptr, wt_atts, 256);
    pack(W_attc, nullptr, wt_attc, 256);
    pack(W1,     nullptr, wt_w1, 1024);

    // ---- degree counts + CSR ----
    hipMemsetAsync(cnt_ss, 0, (size_t)Ns * 4, stream);
    hipMemsetAsync(cnt_sn, 0, (size_t)Ne * 4, stream);
    hipMemsetAsync(cnt_ns, 0, (size_t)Ns * 4, stream);
    count_edges<<<(Ess + 255) / 256, 256, 0, stream>>>(dst_ss, Ess, cnt_ss);
    count_edges<<<(Esn + 255) / 256, 256, 0, stream>>>(dst_sn, Esn, cnt_sn);
    count_edges<<<(Ens + 255) / 256, 256, 0, stream>>>(dst_ns, Ens, cnt_ns);
    make_inv<<<(Ns + 255) / 256, 256, 0, stream>>>(cnt_ss, inv_ss, Ns);
    make_inv<<<(Ne + 255) / 256, 256, 0, stream>>>(cnt_sn, inv_sn, Ne);
    make_inv<<<(Ns + 255) / 256, 256, 0, stream>>>(cnt_ns, inv_ns, Ns);
    auto build_csr = [&](const int* src, const int* dst, int E, int Nd,
                         const int* cnt, int* rowptr, int* colidx) {
        int nb = (Nd + 255) / 256;
        scan1<<<nb, 256, 0, stream>>>(cnt, Nd, rowptr, bsums);
        scan2<<<1, 256, 0, stream>>>(bsums, nb);
        scan3<<<nb, 256, 0, stream>>>(rowptr, bsums, Nd);
        hipMemsetAsync(fillc, 0, (size_t)Nd * 4, stream);
        csr_fill<<<(E + 255) / 256, 256, 0, stream>>>(src, dst, E, rowptr, fillc, colidx);
    };
    build_csr(src_ss, dst_ss, Ess, Ns, cnt_ss, rp_ss, col_ss);
    build_csr(src_sn, dst_sn, Esn, Ne, cnt_sn, rp_sn, col_sn);
    build_csr(src_ns, dst_ns, Ens, Ns, cnt_ns, rp_ns, col_ns);

    // batch segment bounds (batch_s sorted)
    batch_bounds<<<(Ns + 1 + 255) / 256, 256, 0, stream>>>(batch_s, Ns, B, rp_b);

    // ---- input projections ----
    gemm(x_s,   wt_ps, b_ps, xs_a, Ns, 768, F_RELU);
    gemm(x_n,   wt_pn, b_pn, xn_a, Ne, 768, F_RELU);
    gemm(claim, wt_pc, b_pc, ch,   B,  768, F_RELU);

    // ---- GNN layers ----
    float* xs_cur = xs_a; float* xs_nxt = xs_b;
    float* xn_cur = xn_a; float* xn_nxt = xn_b;
    for (int l = 0; l < L; ++l) {
        const float* bl = conv_bl + (size_t)l * 3 * H;

        gather_mean<<<(unsigned)(((long long)Ns * 64 + 255) / 256), 256, 0, stream>>>(
            xs_cur, rp_ss, col_ss, inv_ss, m_big, Ns);
        gemm(m_big, wt_l0[l], bsum[l], xs_nxt, Ns, 256, 0);

        gather_mean<<<(unsigned)(((long long)Ns * 64 + 255) / 256), 256, 0, stream>>>(
            xn_cur, rp_ns, col_ns, inv_ns, m_big, Ns);
        gemm(m_big, wt_l2[l], nullptr, xs_nxt, Ns, 256, F_ACC);

        gemm(xs_cur, wt_rs[l], nullptr, xs_nxt, Ns, 256, F_ACC | F_RELU);

        gather_mean<<<(unsigned)(((long long)Ne * 64 + 255) / 256), 256, 0, stream>>>(
            xs_cur, rp_sn, col_sn, inv_sn, m_big, Ne);
        gemm(m_big, wt_l1[l], bl + H, xn_nxt, Ne, 256, 0);
        gemm(xn_cur, wt_r1[l], nullptr, xn_nxt, Ne, 256, F_ACC | F_RELU);

        float* t;
        t = xs_cur; xs_cur = xs_nxt; xs_nxt = t;
        t = xn_cur; xn_cur = xn_nxt; xn_nxt = t;
    }

    // ---- attentive pooling (segmented, no atomics) ----
    gemm(ch,     wt_attc, nullptr, c_att, B,  256, 0);
    gemm(xs_cur, wt_atts, nullptr, m_big, Ns, 256, 0);   // s_att in m_big
    scores_kernel<<<(unsigned)(((long long)Ns * 64 + 255) / 256), 256, 0, stream>>>(
        m_big, c_att, batch_s, scores, Ns);
    pool_kernel<<<B, 256, 0, stream>>>(scores, xs_cur, rp_b, g);

    // ---- head MLP ----
    z_kernel<<<(B * H + 255) / 256, 256, 0, stream>>>(ch, g, z, B, H);
    gemm(z, wt_w1, b1, hbuf, B, 1024, F_RELU);
    out_kernel<<<(B * 2 + 255) / 256, 256, 0, stream>>>(hbuf, W2, b2, (float*)d_out, B, 256);
}